// Round 3
// baseline (569.306 us; speedup 1.0000x reference)
//
#include <hip/hip_runtime.h>
#include <hip/hip_bf16.h>

#define NH      12
#define HD      64
#define HID     768
#define B_      2
#define D_      16
#define QL      32
#define SL      512
#define SEQ     545
#define RPB     8225
#define TOT_ROWS 16450
#define PAD_ROWS 16512       // 344*48 = 129*128
#define VT_R    8256         // Vt rows/batch: cls=0, query 1..32, doc d at 40+d*512
#define WSZ     589824       // 768*768
#define SCALE_  0.125f
#define LOG2E   1.4426950408889634f

typedef __attribute__((ext_vector_type(8))) short short8;
typedef __attribute__((ext_vector_type(4))) short short4v;
typedef __attribute__((ext_vector_type(4))) float float4v;

__device__ __forceinline__ short f2bf(float f) {
    __hip_bfloat16 h = __float2bfloat16(f);
    short s; __builtin_memcpy(&s, &h, 2);
    return s;
}

// async global->LDS 16B/lane; lds base must be wave-uniform (HW adds lane*16),
// gptr is per-lane (gather allowed on the global side).
__device__ __forceinline__ void gl2lds16(const short* g, short* l) {
    __builtin_amdgcn_global_load_lds(
        (const __attribute__((address_space(1))) void*)g,
        (__attribute__((address_space(3))) void*)l, 16, 0, 0);
}

// ---------------------------------------------------------------------------
// Kernel 1: gather cls/query/doc fp32 -> bf16 X [PAD_ROWS x 768] (linear)
// ---------------------------------------------------------------------------
__global__ __launch_bounds__(256) void pack_kernel(
    const float* __restrict__ cls, const float* __restrict__ query,
    const float* __restrict__ doc, short* __restrict__ X)
{
    int idx = (blockIdx.x * 256 + threadIdx.x) * 4;
    int row = idx / HID;
    int col = idx - row * HID;
    float4 v = make_float4(0.f, 0.f, 0.f, 0.f);
    if (row < TOT_ROWS) {
        int b = row / RPB;
        int r = row - b * RPB;
        const float* src;
        if (r == 0)        src = cls   + b * HID + col;
        else if (r < 33)   src = query + ((size_t)(b * QL + (r - 1))) * HID + col;
        else               src = doc   + ((size_t)(b * (D_ * SL) + (r - 33))) * HID + col;
        v = *reinterpret_cast<const float4*>(src);
    }
    short4v o;
    o[0] = f2bf(v.x); o[1] = f2bf(v.y); o[2] = f2bf(v.z); o[3] = f2bf(v.w);
    *reinterpret_cast<short4v*>(X + idx) = o;
}

// ---------------------------------------------------------------------------
// Kernel 1b: W fp32 -> bf16 (Wb in d_out head; attn fully overwrites later)
// ---------------------------------------------------------------------------
__global__ __launch_bounds__(256) void wpack_kernel(
    const float* __restrict__ Wq, const float* __restrict__ Wk,
    const float* __restrict__ Wv, short* __restrict__ Wb)
{
    int idx = (blockIdx.x * 256 + threadIdx.x) * 4;
    int z = idx / WSZ;
    int r = idx - z * WSZ;
    const float* src = (z == 0 ? Wq : (z == 1 ? Wk : Wv)) + r;
    float4 v = *reinterpret_cast<const float4*>(src);
    short4v o;
    o[0] = f2bf(v.x); o[1] = f2bf(v.y); o[2] = f2bf(v.z); o[3] = f2bf(v.w);
    *reinterpret_cast<short4v*>(Wb + idx) = o;
}

// ---------------------------------------------------------------------------
// Kernel 2: X-stationary projection GEMM.
// Block: 48 X-rows (LDS, staged once, XOR-swizzled 16B chunks) x 1152 output
// cols (n-half). 8 waves, each wave: 3 m-frags x 9 n-frags, K=768 inner loop
// with NO barriers: A from LDS (imm-offset ds_read_b128), B direct from
// global W (L2-resident, imm-offset dwordx4), 27 MFMA per k-step.
// ---------------------------------------------------------------------------
__global__ __launch_bounds__(512, 2) void proj3(
    const short* __restrict__ X, const short* __restrict__ Wb,
    const float* __restrict__ bq, const float* __restrict__ bk,
    const float* __restrict__ bv,
    short* __restrict__ Qb, short* __restrict__ Kb, short* __restrict__ Vt)
{
    __shared__ short Xs[48 * 768];   // 73728 B

    int tid  = threadIdx.x;
    int lane = tid & 63, wave = tid >> 6;
    int lr = lane & 15, lg = lane >> 4;
    int mblk = blockIdx.x;           // 0..343
    int m0 = mblk * 48;
    int nb = blockIdx.y * 1152 + wave * 144;   // wave's n-base (9 frags)

    // ---- stage X tile: 4608 slots of 16B, 9 rounds. LDS slot (r,c) holds
    // global chunk (c&0xF8)|((c&7)^(r&7))  -> frag reads bank-spread.
    for (int p = 0; p < 9; ++p) {
        int s = p * 512 + tid;
        int r = s / 96, c = s - r * 96;
        int cswz = (c & 0xF8) | ((c & 7) ^ (r & 7));
        const short* g = X + (size_t)(m0 + r) * HID + cswz * 8;
        short* lbase = &Xs[(size_t)(p * 512 + (tid & 0x1C0)) * 8];
        gl2lds16(g, lbase);
    }
    __syncthreads();   // drains vmcnt before any ds_read

    // ---- B pointers (per-lane): frag i covers cols nb+i*16 .. +15
    const short* wp[9];
    int zfr[9], cfr[9];
    for (int i = 0; i < 9; ++i) {
        int gc = nb + i * 16 + lr;
        int z = gc / HID;
        int wr = gc - z * HID;
        zfr[i] = z; cfr[i] = wr;     // for epilogue (lr col)
        wp[i] = Wb + (size_t)z * WSZ + (size_t)wr * HID + lg * 8;
    }
    // ---- A ds bases: row r=mi*16+lr, parity q in {0,1}:
    // shorts addr = r*768 + (((q*4+lg) ^ (r&7)))*8  + (kt>>1)*64
    int abase[3][2];
    for (int mi = 0; mi < 3; ++mi) {
        int r = mi * 16 + lr;
        abase[mi][0] = r * HID + ((lg ^ (r & 7)) * 8);
        abase[mi][1] = r * HID + (((4 + lg) ^ (r & 7)) * 8);
    }

    float4v acc[3][9];
    for (int mi = 0; mi < 3; ++mi)
        for (int i = 0; i < 9; ++i)
            acc[mi][i] = (float4v){0.f, 0.f, 0.f, 0.f};

#pragma unroll
    for (int kt = 0; kt < 24; ++kt) {
        const int aoff = (kt >> 1) * 64;
        const int par  = kt & 1;
        short8 a[3], b[9];
        for (int mi = 0; mi < 3; ++mi)
            a[mi] = *reinterpret_cast<const short8*>(&Xs[abase[mi][par] + aoff]);
        for (int i = 0; i < 9; ++i)
            b[i] = *reinterpret_cast<const short8*>(wp[i] + kt * 32);
        for (int mi = 0; mi < 3; ++mi)
            for (int i = 0; i < 9; ++i)
                acc[mi][i] = __builtin_amdgcn_mfma_f32_16x16x32_bf16(
                    a[mi], b[i], acc[mi][i], 0, 0, 0);
    }

    // ---- epilogue
    for (int i = 0; i < 9; ++i) {
        int z = zfr[i], c = cfr[i];
        float bb = (z == 0 ? bq : (z == 1 ? bk : bv))[c];
        if (z < 2) {
            short* Y = z == 0 ? Qb : Kb;
            for (int mi = 0; mi < 3; ++mi) {
                int growb = m0 + mi * 16 + lg * 4;
                for (int r = 0; r < 4; ++r)
                    Y[(size_t)(growb + r) * HID + c] = f2bf(acc[mi][i][r] + bb);
            }
        } else {
            for (int mi = 0; mi < 3; ++mi) {
                int growb = m0 + mi * 16 + lg * 4;
                for (int r = 0; r < 4; ++r) {
                    int grow = growb + r;
                    if (grow >= TOT_ROWS) continue;
                    int b  = grow >= RPB ? 1 : 0;
                    int rb = grow - b * RPB;
                    int vr = rb < 33 ? rb : rb + 7;
                    Vt[((size_t)(b * HID + c)) * VT_R + vr] = f2bf(acc[mi][i][r] + bb);
                }
            }
        }
    }
}

// ---------------------------------------------------------------------------
// Kernel 3: flash attention, S^T form, 128 q per block (2 sets of 64).
// K/V tiles staged to LDS via swizzled gl2lds gather (chunk c at slot
// c^(row&7)); P round-trips per-wave LDS. Internal token order: doc 0..511,
// cls 512, query 513..544, pad 545.. (mask -inf).
// Grid: x = h*32 + bd (same-(h,bd) blocks 384 apart -> same XCD), y = qchunk.
// ---------------------------------------------------------------------------
__device__ __forceinline__ int row_of(int b, int d, int t) {
    t = t > 544 ? 544 : t;
    int base = b * RPB;
    if (t < 512)  return base + 33 + d * SL + t;
    if (t == 512) return base;
    return base + (t - 512);
}

__global__ __launch_bounds__(256) void attn3(
    const short* __restrict__ Qb, const short* __restrict__ Kb,
    const short* __restrict__ Vt,
    const float* __restrict__ qmask, const float* __restrict__ dmask,
    float* __restrict__ out)
{
    __shared__ short Ks[64 * 64];     // [key][dim-chunk swizzled]  8KB
    __shared__ short Vs[64 * 64];     // [dim][key-chunk swizzled]  8KB
    __shared__ short Ps[4][16 * 72];
    __shared__ float maskv[576];

    int tid  = threadIdx.x;
    int lane = tid & 63, wave = tid >> 6;
    int hbd = blockIdx.x;
    int h = hbd >> 5, bd = hbd & 31;
    int b = bd >> 4, d = bd & 15;
    int qc = blockIdx.y;
    int lr = lane & 15, lg = lane >> 4, lk = lg * 8;
    int base = b * RPB;

    for (int i = tid; i < 576; i += 256) {
        float mv;
        if (i < 512)       mv = dmask[(size_t)(b * D_ + d) * SL + i];
        else if (i == 512) mv = 0.f;
        else if (i < 545)  mv = qmask[b * QL + (i - 513)];
        else               mv = -INFINITY;
        maskv[i] = mv * LOG2E;
    }

    // Q frags (B operand, n=q=lr), 2 sets
    short8 bq0[2], bq1[2];
    for (int s = 0; s < 2; ++s) {
        int qtok = qc * 128 + s * 64 + wave * 16 + lr;
        int qrow = qtok < 512 ? base + 33 + d * SL + qtok : base + qtok - 512;
        const short* qp = Qb + (size_t)qrow * HID + h * HD + lk;
        bq0[s] = *reinterpret_cast<const short8*>(qp);
        bq1[s] = *reinterpret_cast<const short8*>(qp + 32);
    }

    float m_i[2] = {-1e30f, -1e30f}, l_i[2] = {0.f, 0.f};
    float4v o[2][4];
    for (int s = 0; s < 2; ++s)
        for (int nt = 0; nt < 4; ++nt) o[s][nt] = (float4v){0.f, 0.f, 0.f, 0.f};

    short* pw = Ps[wave];
    const float qs = SCALE_ * LOG2E;
    const short* vbase = Vt + (size_t)(b * HID + h * HD) * VT_R;

    for (int kt = 0; kt < 9; ++kt) {
        __syncthreads();
        // stage K tile: slot s2=(r<<3)|c holds K[token kt*64+r][chunk c^(r&7)]
        for (int p = 0; p < 2; ++p) {
            int s2 = p * 256 + tid;
            int r = s2 >> 3, c = s2 & 7;
            int t = kt * 64 + r;
            const short* g = Kb + (size_t)row_of(b, d, t) * HID + h * HD
                           + ((c ^ (r & 7)) * 8);
            gl2lds16(g, &Ks[(size_t)(p * 256 + (tid & 0xC0)) * 8]);
        }
        // stage V tile: slot (rd,c): Vt[dim rd][token-chunk (c^(rd&7))]
        for (int p = 0; p < 2; ++p) {
            int s2 = p * 256 + tid;
            int rd = s2 >> 3, c = s2 & 7;
            int tc = kt * 64 + ((c ^ (rd & 7)) * 8);
            int vr = tc < 512 ? 40 + d * SL + tc : tc - 512;
            const short* g = vbase + (size_t)rd * VT_R + vr;
            gl2lds16(g, &Vs[(size_t)(p * 256 + (tid & 0xC0)) * 8]);
        }
        __syncthreads();

        // K frags (A operand), shared by both q-sets
        short8 kf0[4], kf1[4];
        for (int nt = 0; nt < 4; ++nt) {
            int r = nt * 16 + lr;
            int x0 = lg ^ (r & 7);
            kf0[nt] = *reinterpret_cast<const short8*>(&Ks[r * 64 + x0 * 8]);
            kf1[nt] = *reinterpret_cast<const short8*>(&Ks[r * 64 + (x0 ^ 4) * 8]);
        }

        for (int s = 0; s < 2; ++s) {
            float p4[4][4];
            for (int nt = 0; nt < 4; ++nt) {
                float4v z = (float4v){0.f, 0.f, 0.f, 0.f};
                z = __builtin_amdgcn_mfma_f32_16x16x32_bf16(kf0[nt], bq0[s], z, 0, 0, 0);
                z = __builtin_amdgcn_mfma_f32_16x16x32_bf16(kf1[nt], bq1[s], z, 0, 0, 0);
                float4v mk = *reinterpret_cast<const float4v*>(
                    &maskv[kt * 64 + nt * 16 + lg * 4]);
                for (int r = 0; r < 4; ++r) p4[nt][r] = z[r] * qs + mk[r];
            }
            // online softmax (log2 domain), per-lane state for q=lr
            float tmx = p4[0][0];
            for (int nt = 0; nt < 4; ++nt)
                for (int r = 0; r < 4; ++r) tmx = fmaxf(tmx, p4[nt][r]);
            tmx = fmaxf(tmx, __shfl_xor(tmx, 16));
            tmx = fmaxf(tmx, __shfl_xor(tmx, 32));
            float mnew = fmaxf(m_i[s], tmx);
            float alpha = exp2f(m_i[s] - mnew);
            m_i[s] = mnew;
            float sum = 0.f;
            for (int nt = 0; nt < 4; ++nt)
                for (int r = 0; r < 4; ++r) {
                    p4[nt][r] = exp2f(p4[nt][r] - mnew);
                    sum += p4[nt][r];
                }
            sum += __shfl_xor(sum, 16);
            sum += __shfl_xor(sum, 32);
            l_i[s] = l_i[s] * alpha + sum;

            // P -> per-wave LDS (transpose to A layout)
            for (int nt = 0; nt < 4; ++nt) {
                short4v pk;
                for (int r = 0; r < 4; ++r) pk[r] = f2bf(p4[nt][r]);
                *reinterpret_cast<short4v*>(&pw[lr * 72 + nt * 16 + lg * 4]) = pk;
            }
            float al[4];
            for (int r = 0; r < 4; ++r) al[r] = __shfl(alpha, lg * 4 + r);
            for (int nt = 0; nt < 4; ++nt)
                for (int r = 0; r < 4; ++r) o[s][nt][r] *= al[r];

            short8 ap0 = *reinterpret_cast<const short8*>(&pw[lr * 72 + lk]);
            short8 ap1 = *reinterpret_cast<const short8*>(&pw[lr * 72 + 32 + lk]);
            for (int nt = 0; nt < 4; ++nt) {
                int rd = nt * 16 + lr;
                int x0 = lg ^ (rd & 7);
                short8 bv0 = *reinterpret_cast<const short8*>(&Vs[rd * 64 + x0 * 8]);
                short8 bv1 = *reinterpret_cast<const short8*>(&Vs[rd * 64 + (x0 ^ 4) * 8]);
                o[s][nt] = __builtin_amdgcn_mfma_f32_16x16x32_bf16(ap0, bv0, o[s][nt], 0, 0, 0);
                o[s][nt] = __builtin_amdgcn_mfma_f32_16x16x32_bf16(ap1, bv1, o[s][nt], 0, 0, 0);
            }
        }
    }

    // epilogue
    for (int s = 0; s < 2; ++s) {
        float li[4];
        for (int r = 0; r < 4; ++r) li[r] = __shfl(l_i[s], lg * 4 + r);
        for (int r = 0; r < 4; ++r) {
            int t = qc * 128 + s * 64 + wave * 16 + lg * 4 + r;
            if (t >= SEQ) continue;
            int seq = t < 512 ? 33 + t : (t == 512 ? 0 : t - 512);
            float inv = 1.f / li[r];
            float* op = out + ((size_t)(bd * SEQ + seq)) * HID + h * HD + lr;
            for (int nt = 0; nt < 4; ++nt)
                op[nt * 16] = o[s][nt][r] * inv;
        }
    }
}

// ---------------------------------------------------------------------------
extern "C" void kernel_launch(void* const* d_in, const int* in_sizes, int n_in,
                              void* d_out, int out_size, void* d_ws, size_t ws_size,
                              hipStream_t stream)
{
    const float* cls   = (const float*)d_in[0];
    const float* query = (const float*)d_in[1];
    const float* doc   = (const float*)d_in[2];
    const float* qmask = (const float*)d_in[3];
    const float* dmask = (const float*)d_in[4];
    const float* Wq = (const float*)d_in[5];
    const float* bq = (const float*)d_in[6];
    const float* Wk = (const float*)d_in[7];
    const float* bk = (const float*)d_in[8];
    const float* Wv = (const float*)d_in[9];
    const float* bv = (const float*)d_in[10];
    float* out = (float*)d_out;

    short* X  = (short*)d_ws;
    size_t seg = (size_t)PAD_ROWS * HID;
    short* Qb = X + seg;
    short* Kb = Qb + seg;
    short* Vt = Kb + seg;                 // 2*768*8256 == seg
    short* Wb = (short*)d_out;            // scratch; attn3 overwrites all of out

    pack_kernel<<<dim3((PAD_ROWS * HID / 4) / 256), 256, 0, stream>>>(cls, query, doc, X);
    wpack_kernel<<<dim3((3 * WSZ / 4) / 256), 256, 0, stream>>>(Wq, Wk, Wv, Wb);
    proj3<<<dim3(PAD_ROWS / 48, 2), 512, 0, stream>>>(X, Wb, bq, bk, bv, Qb, Kb, Vt);
    attn3<<<dim3(NH * 32, 5), 256, 0, stream>>>(Qb, Kb, Vt, qmask, dmask, out);
}

// Round 4
// 349.260 us; speedup vs baseline: 1.6300x; 1.6300x over previous
//
#include <hip/hip_runtime.h>
#include <hip/hip_bf16.h>

#define NH      12
#define HD      64
#define HID     768
#define B_      2
#define D_      16
#define QL      32
#define SL      512
#define SEQ     545
#define RPB     8225
#define TOT_ROWS 16450
#define PAD_ROWS 16512       // 129*128
#define VT_R    8256         // Vt rows/batch: cls=0, query 1..32, doc d at 40+d*512
#define WSZ     589824       // 768*768
#define SCALE_  0.125f
#define LOG2E   1.4426950408889634f

typedef __attribute__((ext_vector_type(8))) short short8;
typedef __attribute__((ext_vector_type(4))) short short4v;
typedef __attribute__((ext_vector_type(4))) float float4v;

__device__ __forceinline__ short f2bf(float f) {
    __hip_bfloat16 h = __float2bfloat16(f);
    short s; __builtin_memcpy(&s, &h, 2);
    return s;
}

// async global->LDS 16B/lane; lds base wave-uniform (HW adds lane*16)
__device__ __forceinline__ void gl2lds16(const short* g, short* l) {
    __builtin_amdgcn_global_load_lds(
        (const __attribute__((address_space(1))) void*)g,
        (__attribute__((address_space(3))) void*)l, 16, 0, 0);
}

// ---------------------------------------------------------------------------
// Kernel 1: gather cls/query/doc fp32 -> bf16 X [PAD_ROWS x 768]
// ---------------------------------------------------------------------------
__global__ __launch_bounds__(256) void pack_kernel(
    const float* __restrict__ cls, const float* __restrict__ query,
    const float* __restrict__ doc, short* __restrict__ X)
{
    int idx = (blockIdx.x * 256 + threadIdx.x) * 4;
    int row = idx / HID;
    int col = idx - row * HID;
    float4 v = make_float4(0.f, 0.f, 0.f, 0.f);
    if (row < TOT_ROWS) {
        int b = row / RPB;
        int r = row - b * RPB;
        const float* src;
        if (r == 0)        src = cls   + b * HID + col;
        else if (r < 33)   src = query + ((size_t)(b * QL + (r - 1))) * HID + col;
        else               src = doc   + ((size_t)(b * (D_ * SL) + (r - 33))) * HID + col;
        v = *reinterpret_cast<const float4*>(src);
    }
    short4v o;
    o[0] = f2bf(v.x); o[1] = f2bf(v.y); o[2] = f2bf(v.z); o[3] = f2bf(v.w);
    *reinterpret_cast<short4v*>(X + idx) = o;
}

// ---------------------------------------------------------------------------
// Kernel 1b: W fp32 -> bf16 (Wb parked in d_out; attn overwrites all of out)
// ---------------------------------------------------------------------------
__global__ __launch_bounds__(256) void wpack_kernel(
    const float* __restrict__ Wq, const float* __restrict__ Wk,
    const float* __restrict__ Wv, short* __restrict__ Wb)
{
    int idx = (blockIdx.x * 256 + threadIdx.x) * 4;
    int z = idx / WSZ;
    int r = idx - z * WSZ;
    const float* src = (z == 0 ? Wq : (z == 1 ? Wk : Wv)) + r;
    float4 v = *reinterpret_cast<const float4*>(src);
    short4v o;
    o[0] = f2bf(v.x); o[1] = f2bf(v.y); o[2] = f2bf(v.z); o[3] = f2bf(v.w);
    *reinterpret_cast<short4v*>(Wb + idx) = o;
}

// ---------------------------------------------------------------------------
// Kernel 2: projection GEMM, m97 tile (128x128, BK=32) but single-barrier
// double-buffered K-loop: stage kt+1 AFTER the barrier, compute kt — loads
// get a full iteration in flight before their drain.
// VSWAP (V projection): A=W-frag, B=X-frag so D[m=wcol][n=xrow]; Vt stores
// become 16-lane contiguous 32B runs along Vt's fast (token) dim.
// ---------------------------------------------------------------------------
template<bool VSWAP>
__global__ __launch_bounds__(256) void proj4(
    const short* __restrict__ X, const short* __restrict__ Wb,
    const float* __restrict__ bq, const float* __restrict__ bk,
    const float* __restrict__ bv,
    short* __restrict__ Qb, short* __restrict__ Kb, short* __restrict__ Vt)
{
    __shared__ short Xs[2][128 * 32];
    __shared__ short Ws[2][128 * 32];

    int tid = threadIdx.x, lane = tid & 63, wave = tid >> 6;
    int zi = VSWAP ? 2 : blockIdx.z;
    const short* W = Wb + (size_t)zi * WSZ;
    int m0 = blockIdx.x * 128, n0 = blockIdx.y * 128;
    int moff = (wave & 1) * 64, noff = (wave >> 1) * 64;
    int lr = lane & 15, lg = lane >> 4, lk = lg * 8;
    int srow = lane >> 2, sk = (lane & 3) * 8;

    const short* xg0 = X + (size_t)(m0 + wave * 32 + srow) * HID + sk;
    const short* xg1 = xg0 + (size_t)16 * HID;
    const short* wg0 = W + (size_t)(n0 + wave * 32 + srow) * HID + sk;
    const short* wg1 = wg0 + (size_t)16 * HID;

    float4v acc[4][4];
    for (int mi = 0; mi < 4; ++mi)
        for (int ni = 0; ni < 4; ++ni)
            acc[mi][ni] = (float4v){0.f, 0.f, 0.f, 0.f};

#define PSTAGE(bufi, kt) do {                                   \
    gl2lds16(xg0 + (kt) * 32, &Xs[bufi][wave * 1024]);          \
    gl2lds16(xg1 + (kt) * 32, &Xs[bufi][wave * 1024 + 512]);    \
    gl2lds16(wg0 + (kt) * 32, &Ws[bufi][wave * 1024]);          \
    gl2lds16(wg1 + (kt) * 32, &Ws[bufi][wave * 1024 + 512]); } while (0)

    PSTAGE(0, 0);
#pragma unroll
    for (int kt = 0; kt < 24; ++kt) {
        __syncthreads();                     // drains stage(kt); prev compute done
        if (kt < 23) PSTAGE((kt + 1) & 1, kt + 1);
        const short* xb = Xs[kt & 1];
        const short* wb = Ws[kt & 1];
        short8 af[4], bf2[4];
        for (int mi = 0; mi < 4; ++mi)
            af[mi]  = *reinterpret_cast<const short8*>(&xb[(moff + mi * 16 + lr) * 32 + lk]);
        for (int ni = 0; ni < 4; ++ni)
            bf2[ni] = *reinterpret_cast<const short8*>(&wb[(noff + ni * 16 + lr) * 32 + lk]);
        for (int mi = 0; mi < 4; ++mi)
            for (int ni = 0; ni < 4; ++ni) {
                if (!VSWAP)
                    acc[mi][ni] = __builtin_amdgcn_mfma_f32_16x16x32_bf16(
                        af[mi], bf2[ni], acc[mi][ni], 0, 0, 0);
                else
                    acc[mi][ni] = __builtin_amdgcn_mfma_f32_16x16x32_bf16(
                        bf2[ni], af[mi], acc[mi][ni], 0, 0, 0);
            }
    }
#undef PSTAGE

    if (!VSWAP) {
        short* Y = zi == 0 ? Qb : Kb;
        const float* bias = zi == 0 ? bq : bk;
        for (int ni = 0; ni < 4; ++ni) {
            int gcol = n0 + noff + ni * 16 + lr;
            float bb = bias[gcol];
            for (int mi = 0; mi < 4; ++mi) {
                int growb = m0 + moff + mi * 16 + lg * 4;
                for (int r = 0; r < 4; ++r)
                    Y[(size_t)(growb + r) * HID + gcol] = f2bf(acc[mi][ni][r] + bb);
            }
        }
    } else {
        // D[m=wcol = noff+ni*16+lg*4+r][n=xrow = moff+mi*16+lr]
        for (int ni = 0; ni < 4; ++ni) {
            float4 b4 = *reinterpret_cast<const float4*>(&bv[n0 + noff + ni * 16 + lg * 4]);
            const float* bbr = reinterpret_cast<const float*>(&b4);
            for (int mi = 0; mi < 4; ++mi) {
                int grow = m0 + moff + mi * 16 + lr;
                if (grow >= TOT_ROWS) continue;
                int b  = grow >= RPB ? 1 : 0;
                int rb = grow - b * RPB;
                int vr = rb < 33 ? rb : rb + 7;        // doc rows at 40+
                size_t cb = ((size_t)(b * HID + n0 + noff + ni * 16 + lg * 4)) * VT_R;
                for (int r = 0; r < 4; ++r)
                    Vt[cb + (size_t)r * VT_R + vr] = f2bf(acc[mi][ni][r] + bbr[r]);
            }
        }
    }
}

// ---------------------------------------------------------------------------
// Kernel 3: flash attention (S^T form, 128 q/block), double-buffered K/V
// staging with a single barrier per key-tile (prefetch after barrier).
// Token order: doc 0..511, cls 512, query 513..544, pad 545.. (-inf mask).
// ---------------------------------------------------------------------------
__device__ __forceinline__ int row_of(int b, int d, int t) {
    t = t > 544 ? 544 : t;
    int base = b * RPB;
    if (t < 512)  return base + 33 + d * SL + t;
    if (t == 512) return base;
    return base + (t - 512);
}

__global__ __launch_bounds__(256) void attn4(
    const short* __restrict__ Qb, const short* __restrict__ Kb,
    const short* __restrict__ Vt,
    const float* __restrict__ qmask, const float* __restrict__ dmask,
    float* __restrict__ out)
{
    __shared__ short Ks[2][64 * 64];
    __shared__ short Vs[2][64 * 64];
    __shared__ short Ps[4][16 * 72];
    __shared__ float maskv[576];

    int tid  = threadIdx.x;
    int lane = tid & 63, wave = tid >> 6;
    int hbd = blockIdx.x;
    int h = hbd >> 5, bd = hbd & 31;
    int b = bd >> 4, d = bd & 15;
    int qc = blockIdx.y;
    int lr = lane & 15, lg = lane >> 4, lk = lg * 8;
    int base = b * RPB;
    const short* vbase = Vt + (size_t)(b * HID + h * HD) * VT_R;

#define ASTAGE(bufi, kt) do {                                               \
    for (int p = 0; p < 2; ++p) {                                           \
        int s2 = p * 256 + tid;                                             \
        int r = s2 >> 3, c = s2 & 7;                                        \
        const short* g = Kb + (size_t)row_of(b, d, (kt) * 64 + r) * HID     \
                       + h * HD + ((c ^ (r & 7)) * 8);                      \
        gl2lds16(g, &Ks[bufi][(p * 256 + (tid & 0xC0)) * 8]);               \
    }                                                                       \
    for (int p = 0; p < 2; ++p) {                                           \
        int s2 = p * 256 + tid;                                             \
        int rd = s2 >> 3, c = s2 & 7;                                       \
        int tc = (kt) * 64 + ((c ^ (rd & 7)) * 8);                          \
        int vr = tc < 512 ? 40 + d * SL + tc : tc - 512;                    \
        gl2lds16(vbase + (size_t)rd * VT_R + vr,                            \
                 &Vs[bufi][(p * 256 + (tid & 0xC0)) * 8]);                  \
    } } while (0)

    ASTAGE(0, 0);

    for (int i = tid; i < 576; i += 256) {
        float mv;
        if (i < 512)       mv = dmask[(size_t)(b * D_ + d) * SL + i];
        else if (i == 512) mv = 0.f;
        else if (i < 545)  mv = qmask[b * QL + (i - 513)];
        else               mv = -INFINITY;
        maskv[i] = mv * LOG2E;
    }

    short8 bq0[2], bq1[2];
    for (int s = 0; s < 2; ++s) {
        int qtok = qc * 128 + s * 64 + wave * 16 + lr;
        int qrow = qtok < 512 ? base + 33 + d * SL + qtok : base + qtok - 512;
        const short* qp = Qb + (size_t)qrow * HID + h * HD + lk;
        bq0[s] = *reinterpret_cast<const short8*>(qp);
        bq1[s] = *reinterpret_cast<const short8*>(qp + 32);
    }

    float m_i[2] = {-1e30f, -1e30f}, l_i[2] = {0.f, 0.f};
    float4v o[2][4];
    for (int s = 0; s < 2; ++s)
        for (int nt = 0; nt < 4; ++nt) o[s][nt] = (float4v){0.f, 0.f, 0.f, 0.f};

    short* pw = Ps[wave];
    const float qs = SCALE_ * LOG2E;

#pragma unroll
    for (int kt = 0; kt < 9; ++kt) {
        __syncthreads();                    // stage(kt) drained; prev compute done
        if (kt < 8) ASTAGE((kt + 1) & 1, kt + 1);
        const short* kb = Ks[kt & 1];
        const short* vbuf = Vs[kt & 1];

        short8 kf0[4], kf1[4];
        for (int nt = 0; nt < 4; ++nt) {
            int r = nt * 16 + lr;
            int x0 = lg ^ (r & 7);
            kf0[nt] = *reinterpret_cast<const short8*>(&kb[r * 64 + x0 * 8]);
            kf1[nt] = *reinterpret_cast<const short8*>(&kb[r * 64 + (x0 ^ 4) * 8]);
        }

        for (int s = 0; s < 2; ++s) {
            float p4[4][4];
            for (int nt = 0; nt < 4; ++nt) {
                float4v z = (float4v){0.f, 0.f, 0.f, 0.f};
                z = __builtin_amdgcn_mfma_f32_16x16x32_bf16(kf0[nt], bq0[s], z, 0, 0, 0);
                z = __builtin_amdgcn_mfma_f32_16x16x32_bf16(kf1[nt], bq1[s], z, 0, 0, 0);
                float4v mk = *reinterpret_cast<const float4v*>(
                    &maskv[kt * 64 + nt * 16 + lg * 4]);
                for (int r = 0; r < 4; ++r) p4[nt][r] = z[r] * qs + mk[r];
            }
            float tmx = p4[0][0];
            for (int nt = 0; nt < 4; ++nt)
                for (int r = 0; r < 4; ++r) tmx = fmaxf(tmx, p4[nt][r]);
            tmx = fmaxf(tmx, __shfl_xor(tmx, 16));
            tmx = fmaxf(tmx, __shfl_xor(tmx, 32));
            float mnew = fmaxf(m_i[s], tmx);
            float alpha = exp2f(m_i[s] - mnew);
            m_i[s] = mnew;
            float sum = 0.f;
            for (int nt = 0; nt < 4; ++nt)
                for (int r = 0; r < 4; ++r) {
                    p4[nt][r] = exp2f(p4[nt][r] - mnew);
                    sum += p4[nt][r];
                }
            sum += __shfl_xor(sum, 16);
            sum += __shfl_xor(sum, 32);
            l_i[s] = l_i[s] * alpha + sum;

            for (int nt = 0; nt < 4; ++nt) {
                short4v pk;
                for (int r = 0; r < 4; ++r) pk[r] = f2bf(p4[nt][r]);
                *reinterpret_cast<short4v*>(&pw[lr * 72 + nt * 16 + lg * 4]) = pk;
            }
            float al[4];
            for (int r = 0; r < 4; ++r) al[r] = __shfl(alpha, lg * 4 + r);
            for (int nt = 0; nt < 4; ++nt)
                for (int r = 0; r < 4; ++r) o[s][nt][r] *= al[r];

            short8 ap0 = *reinterpret_cast<const short8*>(&pw[lr * 72 + lk]);
            short8 ap1 = *reinterpret_cast<const short8*>(&pw[lr * 72 + 32 + lk]);
            for (int nt = 0; nt < 4; ++nt) {
                int rd = nt * 16 + lr;
                int x0 = lg ^ (rd & 7);
                short8 bv0 = *reinterpret_cast<const short8*>(&vbuf[rd * 64 + x0 * 8]);
                short8 bv1 = *reinterpret_cast<const short8*>(&vbuf[rd * 64 + (x0 ^ 4) * 8]);
                o[s][nt] = __builtin_amdgcn_mfma_f32_16x16x32_bf16(ap0, bv0, o[s][nt], 0, 0, 0);
                o[s][nt] = __builtin_amdgcn_mfma_f32_16x16x32_bf16(ap1, bv1, o[s][nt], 0, 0, 0);
            }
        }
    }
#undef ASTAGE

    for (int s = 0; s < 2; ++s) {
        float li[4];
        for (int r = 0; r < 4; ++r) li[r] = __shfl(l_i[s], lg * 4 + r);
        for (int r = 0; r < 4; ++r) {
            int t = qc * 128 + s * 64 + wave * 16 + lg * 4 + r;
            if (t >= SEQ) continue;
            int seq = t < 512 ? 33 + t : (t == 512 ? 0 : t - 512);
            float inv = 1.f / li[r];
            float* op = out + ((size_t)(bd * SEQ + seq)) * HID + h * HD + lr;
            for (int nt = 0; nt < 4; ++nt)
                op[nt * 16] = o[s][nt][r] * inv;
        }
    }
}

// ---------------------------------------------------------------------------
extern "C" void kernel_launch(void* const* d_in, const int* in_sizes, int n_in,
                              void* d_out, int out_size, void* d_ws, size_t ws_size,
                              hipStream_t stream)
{
    const float* cls   = (const float*)d_in[0];
    const float* query = (const float*)d_in[1];
    const float* doc   = (const float*)d_in[2];
    const float* qmask = (const float*)d_in[3];
    const float* dmask = (const float*)d_in[4];
    const float* Wq = (const float*)d_in[5];
    const float* bq = (const float*)d_in[6];
    const float* Wk = (const float*)d_in[7];
    const float* bk = (const float*)d_in[8];
    const float* Wv = (const float*)d_in[9];
    const float* bv = (const float*)d_in[10];
    float* out = (float*)d_out;

    short* X  = (short*)d_ws;
    size_t seg = (size_t)PAD_ROWS * HID;
    short* Qb = X + seg;
    short* Kb = Qb + seg;
    short* Vt = Kb + seg;                 // 2*768*8256 == seg
    short* Wb = (short*)d_out;            // scratch; attn4 overwrites all of out

    pack_kernel<<<dim3((PAD_ROWS * HID / 4) / 256), 256, 0, stream>>>(cls, query, doc, X);
    wpack_kernel<<<dim3((3 * WSZ / 4) / 256), 256, 0, stream>>>(Wq, Wk, Wv, Wb);
    proj4<false><<<dim3(129, 6, 2), 256, 0, stream>>>(X, Wb, bq, bk, bv, Qb, Kb, Vt);
    proj4<true ><<<dim3(129, 6, 1), 256, 0, stream>>>(X, Wb, bq, bk, bv, Qb, Kb, Vt);
    attn4<<<dim3(NH * 32, 5), 256, 0, stream>>>(Qb, Kb, Vt, qmask, dmask, out);
}